// Round 6
// baseline (420.882 us; speedup 1.0000x reference)
//
#include <hip/hip_runtime.h>
#include <hip/hip_bf16.h>
#include <math.h>

// B,H,S,D = 4,16,1024,64 ; out[b,h,d] = sum_q (softmax(QK^T/sqrt(D)) @ V)[q,d]
//                                     = sum_k w[k]*V[k,d],  w[k] = sum_q attn[q,k]
#define BB 4
#define HH 16
#define SS 1024
#define DD 64

typedef __attribute__((ext_vector_type(8))) short bf16x8;
typedef __attribute__((ext_vector_type(4))) float f32x4;

#define MFMA_BF16 __builtin_amdgcn_mfma_f32_16x16x32_bf16

__device__ __forceinline__ float4 ld4f(const float* p) {
    return *reinterpret_cast<const float4*>(p);
}

// split fp32 x into bf16 hi + bf16 lo (x ~= hi + lo, |lo| <= 2^-9 |x|)
__device__ __forceinline__ void bsplit(float x, short& h, short& l) {
    __hip_bfloat16 bh = __float2bfloat16(x);
    float rem = x - __bfloat162float(bh);
    __hip_bfloat16 bl = __float2bfloat16(rem);
    h = *reinterpret_cast<short*>(&bh);
    l = *reinterpret_cast<short*>(&bl);
}

// prep: K fp32 -> Kh, Kl bf16 arrays (workspace)
__global__ __launch_bounds__(256)
void split_kernel(const float* __restrict__ in, short* __restrict__ hi,
                  short* __restrict__ lo, int n4) {
    const float4* in4 = reinterpret_cast<const float4*>(in);
    for (int i = blockIdx.x * blockDim.x + threadIdx.x; i < n4;
         i += gridDim.x * blockDim.x) {
        float4 v = in4[i];
        short h0, h1, h2, h3, l0, l1, l2, l3;
        bsplit(v.x, h0, l0); bsplit(v.y, h1, l1);
        bsplit(v.z, h2, l2); bsplit(v.w, h3, l3);
        short4 hv = {h0, h1, h2, h3};
        short4 lv = {l0, l1, l2, l3};
        reinterpret_cast<short4*>(hi)[i] = hv;
        reinterpret_cast<short4*>(lo)[i] = lv;
    }
}

// prep: int32 mask -> bit mask (1 bit per element), wave-ballot packed.
// bits[w] covers elements 64w..64w+63, bit i = (mask[64w+i] != 0).
__global__ __launch_bounds__(256)
void maskbits_kernel(const int* __restrict__ mask,
                     unsigned long long* __restrict__ bits) {
    const int tid = blockIdx.x * blockDim.x + threadIdx.x;
    const int widx = tid >> 6;
    const int lane = tid & 63;
    const unsigned long long bal = __ballot(mask[(size_t)widx * 64 + lane] != 0);
    if (lane == 0) bits[widx] = bal;
}

constexpr int QT = 64;   // q rows per block; 4 waves x 16 rows
constexpr int MW = SS / 32;  // mask words per row (uint32 granularity)

// PRESPLIT: K fragments from pre-split bf16 hi/lo arrays in workspace,
//           else split fp32 K in registers.
// MBITS   : mask from packed bitmask, else raw int32 loads.
template <bool PRESPLIT, bool MBITS>
__global__ __launch_bounds__(256, 4)
void attn_mfma(const float* __restrict__ Q, const short* __restrict__ Kh,
               const short* __restrict__ Kl, const float* __restrict__ Kf,
               const float* __restrict__ V, const int* __restrict__ mask,
               const unsigned int* __restrict__ mbits, float* __restrict__ out) {
    __shared__ float w_lds[4][SS];   // per-wave column sums, 16 KB
    __shared__ float red[4][64];

    const int bid = blockIdx.x;
    const int bh  = bid & 63;             // same-bh tiles share XCD (bid%8=bh%8)
    const int qt  = bid >> 6;             // 0..15
    const int b   = bh >> 4;              // bh / HH
    const int tid  = threadIdx.x;
    const int wave = tid >> 6;
    const int lane = tid & 63;
    const int lg = lane >> 4;             // k-group / row-quarter
    const int lr = lane & 15;             // A row / B col within tile

    const size_t bhoff = (size_t)bh * SS * DD;
    const int qbase = qt * QT + wave * 16;   // this wave's 16 q rows

    // ---- preload Q fragments (scaled by 1/sqrt(D), split hi/lo) ----
    bf16x8 qh0, qh1, ql0, ql1;
    {
        auto loadq = [&](int d, bf16x8& H, bf16x8& L) {
            const float* qp = Q + bhoff + (size_t)(qbase + lr) * DD + d * 32 + lg * 8;
            float4 a = ld4f(qp), c = ld4f(qp + 4);
            float xs[8] = {a.x, a.y, a.z, a.w, c.x, c.y, c.z, c.w};
            #pragma unroll
            for (int j = 0; j < 8; ++j) {
                short hh, ll;
                bsplit(xs[j] * 0.125f, hh, ll);
                H[j] = hh; L[j] = ll;
            }
        };
        loadq(0, qh0, ql0);
        loadq(1, qh1, ql1);
    }

    // per-r mask row bases
    size_t mrow[4];   // bitmask: word-row base; raw: element-row base
    #pragma unroll
    for (int r = 0; r < 4; ++r) {
        const size_t row = (size_t)b * SS + (qbase + lg * 4 + r);
        mrow[r] = MBITS ? row * MW : row * SS + lr;
    }

    const short* khp = Kh + bhoff + (size_t)lr * DD + lg * 8;
    const short* klp = Kl + bhoff + (size_t)lr * DD + lg * 8;
    const float* kfp = Kf + bhoff + (size_t)lr * DD + lg * 8;

    auto qk_tile = [&](int n0, f32x4& acc) {
        bf16x8 kh0, kh1, kl0, kl1;
        if constexpr (PRESPLIT) {
            const short* kp = khp + (size_t)n0 * DD;
            kh0 = *(const bf16x8*)kp;
            kh1 = *(const bf16x8*)(kp + 32);
            const short* lp = klp + (size_t)n0 * DD;
            kl0 = *(const bf16x8*)lp;
            kl1 = *(const bf16x8*)(lp + 32);
        } else {
            const float* kp = kfp + (size_t)n0 * DD;
            float4 a = ld4f(kp), c = ld4f(kp + 4);
            float4 e = ld4f(kp + 32), g = ld4f(kp + 36);
            float x0[8] = {a.x, a.y, a.z, a.w, c.x, c.y, c.z, c.w};
            float x1[8] = {e.x, e.y, e.z, e.w, g.x, g.y, g.z, g.w};
            #pragma unroll
            for (int j = 0; j < 8; ++j) {
                short hh, ll;
                bsplit(x0[j], hh, ll);
                kh0[j] = hh; kl0[j] = ll;
                bsplit(x1[j], hh, ll);
                kh1[j] = hh; kl1[j] = ll;
            }
        }
        acc = MFMA_BF16(qh0, kh0, acc, 0, 0, 0);
        acc = MFMA_BF16(qh1, kh1, acc, 0, 0, 0);
        acc = MFMA_BF16(qh0, kl0, acc, 0, 0, 0);
        acc = MFMA_BF16(qh1, kl1, acc, 0, 0, 0);
        acc = MFMA_BF16(ql0, kh0, acc, 0, 0, 0);
        acc = MFMA_BF16(ql1, kh1, acc, 0, 0, 0);
    };

    // mask bit for (row r, col n0+lr); mw valid when MBITS
    auto mtest = [&](const unsigned int* mw, int r, int n0) -> bool {
        if constexpr (MBITS)
            return (mw[r] >> ((n0 & 16) + lr)) & 1u;
        else
            return mask[mrow[r] + n0] != 0;
    };

    // =============== PASS 1: row exp-sums l[q] ===============
    float lacc[4] = {0.f, 0.f, 0.f, 0.f};

    for (int n0 = 0; n0 < SS; n0 += 32) {
        unsigned int mw[4];
        if constexpr (MBITS) {
            #pragma unroll
            for (int r = 0; r < 4; ++r) mw[r] = mbits[mrow[r] + (n0 >> 5)];
        }
        f32x4 a0 = {0.f, 0.f, 0.f, 0.f};
        qk_tile(n0, a0);
        #pragma unroll
        for (int r = 0; r < 4; ++r)
            lacc[r] += mtest(mw, r, n0) ? __expf(a0[r]) : 0.0f;

        f32x4 a1 = {0.f, 0.f, 0.f, 0.f};
        qk_tile(n0 + 16, a1);
        #pragma unroll
        for (int r = 0; r < 4; ++r)
            lacc[r] += mtest(mw, r, n0 + 16) ? __expf(a1[r]) : 0.0f;
    }

    // reduce over the 16 col-lanes (same lg group) -> 1/l per row
    float invl[4];
    #pragma unroll
    for (int r = 0; r < 4; ++r) {
        float v = lacc[r];
        v += __shfl_xor(v, 1);
        v += __shfl_xor(v, 2);
        v += __shfl_xor(v, 4);
        v += __shfl_xor(v, 8);
        invl[r] = 1.0f / v;
    }

    // =============== PASS 2: w[col] = sum_q attn[q,col] ===============
    for (int n0 = 0; n0 < SS; n0 += 32) {
        unsigned int mw[4];
        if constexpr (MBITS) {
            #pragma unroll
            for (int r = 0; r < 4; ++r) mw[r] = mbits[mrow[r] + (n0 >> 5)];
        }
        f32x4 a0 = {0.f, 0.f, 0.f, 0.f};
        qk_tile(n0, a0);
        float wp0 = 0.0f;
        #pragma unroll
        for (int r = 0; r < 4; ++r)
            wp0 += mtest(mw, r, n0) ? __expf(a0[r]) * invl[r] : 0.0f;
        wp0 += __shfl_xor(wp0, 16);
        wp0 += __shfl_xor(wp0, 32);
        if (lane < 16) w_lds[wave][n0 + lr] = wp0;

        f32x4 a1 = {0.f, 0.f, 0.f, 0.f};
        qk_tile(n0 + 16, a1);
        float wp1 = 0.0f;
        #pragma unroll
        for (int r = 0; r < 4; ++r)
            wp1 += mtest(mw, r, n0 + 16) ? __expf(a1[r]) * invl[r] : 0.0f;
        wp1 += __shfl_xor(wp1, 16);
        wp1 += __shfl_xor(wp1, 32);
        if (lane < 16) w_lds[wave][n0 + 16 + lr] = wp1;
    }
    __syncthreads();

    // combine 4 waves' w, then out[d] += sum_c w[c] * V[c][d]
    for (int c = tid; c < SS; c += 256)
        w_lds[0][c] = w_lds[0][c] + w_lds[1][c] + w_lds[2][c] + w_lds[3][c];
    __syncthreads();

    const int d  = tid & 63;
    const int kg = tid >> 6;
    float oacc = 0.0f;
    for (int c = kg; c < SS; c += 4)
        oacc = fmaf(w_lds[0][c], V[bhoff + (size_t)c * DD + d], oacc);
    red[kg][d] = oacc;
    __syncthreads();
    if (kg == 0)
        atomicAdd(&out[bh * DD + d], red[0][d] + red[1][d] + red[2][d] + red[3][d]);
}

extern "C" void kernel_launch(void* const* d_in, const int* in_sizes, int n_in,
                              void* d_out, int out_size, void* d_ws, size_t ws_size,
                              hipStream_t stream) {
    const float* Q    = (const float*)d_in[0];
    const float* K    = (const float*)d_in[1];
    const float* V    = (const float*)d_in[2];
    const int*   mask = (const int*)d_in[3];
    float* out = (float*)d_out;

    const size_t nelem    = (size_t)BB * HH * SS * DD;     // 4.19M
    const size_t mb_bytes = (size_t)BB * SS * SS / 8;      // 512 KB
    const size_t k_bytes  = 2 * nelem * sizeof(short);     // 16.8 MB

    hipMemsetAsync(out, 0, (size_t)BB * HH * DD * sizeof(float), stream);

    const dim3 grid(BB * HH * (SS / QT));                  // 1024 blocks

    if (ws_size >= mb_bytes + k_bytes) {
        unsigned long long* mb = (unsigned long long*)d_ws;
        short* Kh = (short*)((char*)d_ws + mb_bytes);
        short* Kl = Kh + nelem;
        maskbits_kernel<<<(BB * SS * SS / 64) * 64 / 256, 256, 0, stream>>>(mask, mb);
        split_kernel<<<1024, 256, 0, stream>>>(K, Kh, Kl, (int)(nelem / 4));
        attn_mfma<true, true><<<grid, 256, 0, stream>>>(
            Q, Kh, Kl, K, V, mask, (const unsigned int*)mb, out);
    } else if (ws_size >= mb_bytes) {
        unsigned long long* mb = (unsigned long long*)d_ws;
        maskbits_kernel<<<(BB * SS * SS / 64) * 64 / 256, 256, 0, stream>>>(mask, mb);
        attn_mfma<false, true><<<grid, 256, 0, stream>>>(
            Q, nullptr, nullptr, K, V, mask, (const unsigned int*)mb, out);
    } else {
        attn_mfma<false, false><<<grid, 256, 0, stream>>>(
            Q, nullptr, nullptr, K, V, mask, nullptr, out);
    }
}

// Round 7
// 304.930 us; speedup vs baseline: 1.3803x; 1.3803x over previous
//
#include <hip/hip_runtime.h>
#include <hip/hip_bf16.h>
#include <math.h>

// B,H,S,D = 4,16,1024,64 ; out[b,h,d] = sum_q (softmax(QK^T/sqrt(D)) @ V)[q,d]
//                                     = sum_k w[k]*V[k,d],  w[k] = sum_q attn[q,k]
#define BB 4
#define HH 16
#define SS 1024
#define DD 64

typedef __attribute__((ext_vector_type(8))) short bf16x8;
typedef __attribute__((ext_vector_type(4))) float f32x4;

#define MFMA_BF16 __builtin_amdgcn_mfma_f32_16x16x32_bf16

__device__ __forceinline__ float4 ld4f(const float* p) {
    return *reinterpret_cast<const float4*>(p);
}

// split fp32 x into bf16 hi + bf16 lo (x ~= hi + lo, |lo| <= 2^-9 |x|)
__device__ __forceinline__ void bsplit(float x, short& h, short& l) {
    __hip_bfloat16 bh = __float2bfloat16(x);
    float rem = x - __bfloat162float(bh);
    __hip_bfloat16 bl = __float2bfloat16(rem);
    h = *reinterpret_cast<short*>(&bh);
    l = *reinterpret_cast<short*>(&bl);
}

// prep: K fp32 -> Kh, Kl bf16 arrays (workspace)
__global__ __launch_bounds__(256)
void split_kernel(const float* __restrict__ in, short* __restrict__ hi,
                  short* __restrict__ lo, int n4) {
    const float4* in4 = reinterpret_cast<const float4*>(in);
    for (int i = blockIdx.x * blockDim.x + threadIdx.x; i < n4;
         i += gridDim.x * blockDim.x) {
        float4 v = in4[i];
        short h0, h1, h2, h3, l0, l1, l2, l3;
        bsplit(v.x, h0, l0); bsplit(v.y, h1, l1);
        bsplit(v.z, h2, l2); bsplit(v.w, h3, l3);
        short4 hv = {h0, h1, h2, h3};
        short4 lv = {l0, l1, l2, l3};
        reinterpret_cast<short4*>(hi)[i] = hv;
        reinterpret_cast<short4*>(lo)[i] = lv;
    }
}

// prep: int32 mask -> bit mask (1 bit per element), wave-ballot packed.
__global__ __launch_bounds__(256)
void maskbits_kernel(const int* __restrict__ mask,
                     unsigned long long* __restrict__ bits) {
    const int tid = blockIdx.x * blockDim.x + threadIdx.x;
    const int widx = tid >> 6;
    const int lane = tid & 63;
    const unsigned long long bal = __ballot(mask[(size_t)widx * 64 + lane] != 0);
    if (lane == 0) bits[widx] = bal;
}

constexpr int QT = 128;      // q rows per block; 4 waves x 2 subtiles of 16
constexpr int MW = SS / 32;  // mask words per row (uint32 granularity)

// PRESPLIT: K fragments from pre-split bf16 hi/lo arrays, else in-register split.
// MBITS   : mask from packed bitmask, else raw int32 loads.
template <bool PRESPLIT, bool MBITS>
__global__ __launch_bounds__(256, 2)
void attn_mfma(const float* __restrict__ Q, const short* __restrict__ Kh,
               const short* __restrict__ Kl, const float* __restrict__ Kf,
               const float* __restrict__ V, const int* __restrict__ mask,
               const unsigned int* __restrict__ mbits, float* __restrict__ out) {
    __shared__ float w_lds[4][SS];   // per-wave column sums, 16 KB
    __shared__ float red[4][64];

    const int bid = blockIdx.x;
    const int nqt = SS / QT;              // 8
    const int qt  = bid % nqt;
    const int bh  = bid / nqt;            // 0..63
    const int b   = bh >> 4;
    const int tid  = threadIdx.x;
    const int wave = tid >> 6;
    const int lane = tid & 63;
    const int lg = lane >> 4;             // k-group / row-quarter
    const int lr = lane & 15;             // A row / B col within tile

    const size_t bhoff = (size_t)bh * SS * DD;
    const int q0 = qt * QT;
    const int m_base = q0 + wave * 32;    // this wave's 32 q rows

    // ---- preload Q fragments (scaled by 1/sqrt(D), split hi/lo) ----
    bf16x8 qh00, qh01, qh10, qh11, ql00, ql01, ql10, ql11;
    {
        auto loadq = [&](int s, int d, bf16x8& H, bf16x8& L) {
            const float* qp = Q + bhoff + (size_t)(m_base + s * 16 + lr) * DD
                              + d * 32 + lg * 8;
            float4 a = ld4f(qp), c = ld4f(qp + 4);
            float xs[8] = {a.x, a.y, a.z, a.w, c.x, c.y, c.z, c.w};
            #pragma unroll
            for (int j = 0; j < 8; ++j) {
                short hh, ll;
                bsplit(xs[j] * 0.125f, hh, ll);
                H[j] = hh; L[j] = ll;
            }
        };
        loadq(0, 0, qh00, ql00); loadq(0, 1, qh01, ql01);
        loadq(1, 0, qh10, ql10); loadq(1, 1, qh11, ql11);
    }

    // mask row bases: row = m_base + s*16 + lg*4 + r
    int mrowW[2][4];   // word-row base (MBITS)
    int mrowE[2][4];   // element-row base (raw)
    #pragma unroll
    for (int s = 0; s < 2; ++s)
        #pragma unroll
        for (int r = 0; r < 4; ++r) {
            const int row = b * SS + m_base + s * 16 + lg * 4 + r;
            mrowW[s][r] = row * MW;
            mrowE[s][r] = row * SS + lr;
        }

    const short* khp = Kh + bhoff + (size_t)lr * DD + lg * 8;
    const short* klp = Kl + bhoff + (size_t)lr * DD + lg * 8;
    const float* kfp = Kf + bhoff + (size_t)lr * DD + lg * 8;

    // 12 MFMAs: two independent acc chains (row subtiles s=0,1)
    auto qk_tile = [&](int n0, f32x4& acc0, f32x4& acc1) {
        bf16x8 kh0, kh1, kl0, kl1;
        if constexpr (PRESPLIT) {
            const short* kp = khp + (size_t)n0 * DD;
            kh0 = *(const bf16x8*)kp;
            kh1 = *(const bf16x8*)(kp + 32);
            const short* lp = klp + (size_t)n0 * DD;
            kl0 = *(const bf16x8*)lp;
            kl1 = *(const bf16x8*)(lp + 32);
        } else {
            const float* kp = kfp + (size_t)n0 * DD;
            float4 a = ld4f(kp), c = ld4f(kp + 4);
            float4 e = ld4f(kp + 32), g = ld4f(kp + 36);
            float x0[8] = {a.x, a.y, a.z, a.w, c.x, c.y, c.z, c.w};
            float x1[8] = {e.x, e.y, e.z, e.w, g.x, g.y, g.z, g.w};
            #pragma unroll
            for (int j = 0; j < 8; ++j) {
                short hh, ll;
                bsplit(x0[j], hh, ll);
                kh0[j] = hh; kl0[j] = ll;
                bsplit(x1[j], hh, ll);
                kh1[j] = hh; kl1[j] = ll;
            }
        }
        acc0 = MFMA_BF16(qh00, kh0, acc0, 0, 0, 0);
        acc1 = MFMA_BF16(qh10, kh0, acc1, 0, 0, 0);
        acc0 = MFMA_BF16(qh01, kh1, acc0, 0, 0, 0);
        acc1 = MFMA_BF16(qh11, kh1, acc1, 0, 0, 0);
        acc0 = MFMA_BF16(qh00, kl0, acc0, 0, 0, 0);
        acc1 = MFMA_BF16(qh10, kl0, acc1, 0, 0, 0);
        acc0 = MFMA_BF16(qh01, kl1, acc0, 0, 0, 0);
        acc1 = MFMA_BF16(qh11, kl1, acc1, 0, 0, 0);
        acc0 = MFMA_BF16(ql00, kh0, acc0, 0, 0, 0);
        acc1 = MFMA_BF16(ql10, kh0, acc1, 0, 0, 0);
        acc0 = MFMA_BF16(ql01, kh1, acc0, 0, 0, 0);
        acc1 = MFMA_BF16(ql11, kh1, acc1, 0, 0, 0);
    };

    // mask test for (subtile s, reg r), column bit = base bit within 32-word
    auto mtest = [&](const unsigned int mw[2][4], int s, int r, int bit,
                     int n0) -> bool {
        if constexpr (MBITS)
            return (mw[s][r] >> bit) & 1u;
        else
            return mask[mrowE[s][r] + n0] != 0;
    };

    // =============== PASS 1: row exp-sums l[q] ===============
    float lacc[2][4];
    #pragma unroll
    for (int s = 0; s < 2; ++s)
        #pragma unroll
        for (int r = 0; r < 4; ++r) lacc[s][r] = 0.0f;

    for (int n0 = 0; n0 < SS; n0 += 32) {
        unsigned int mw[2][4];
        if constexpr (MBITS) {
            #pragma unroll
            for (int s = 0; s < 2; ++s)
                #pragma unroll
                for (int r = 0; r < 4; ++r)
                    mw[s][r] = mbits[mrowW[s][r] + (n0 >> 5)];
        }
        {
            f32x4 a0 = {0.f, 0.f, 0.f, 0.f}, a1 = {0.f, 0.f, 0.f, 0.f};
            qk_tile(n0, a0, a1);
            #pragma unroll
            for (int r = 0; r < 4; ++r) {
                lacc[0][r] += mtest(mw, 0, r, lr, n0) ? __expf(a0[r]) : 0.0f;
                lacc[1][r] += mtest(mw, 1, r, lr, n0) ? __expf(a1[r]) : 0.0f;
            }
        }
        {
            f32x4 a0 = {0.f, 0.f, 0.f, 0.f}, a1 = {0.f, 0.f, 0.f, 0.f};
            qk_tile(n0 + 16, a0, a1);
            #pragma unroll
            for (int r = 0; r < 4; ++r) {
                lacc[0][r] += mtest(mw, 0, r, 16 + lr, n0 + 16) ? __expf(a0[r]) : 0.0f;
                lacc[1][r] += mtest(mw, 1, r, 16 + lr, n0 + 16) ? __expf(a1[r]) : 0.0f;
            }
        }
    }

    // reduce over the 16 col-lanes (same lg group) -> 1/l per row
    float invl[2][4];
    #pragma unroll
    for (int s = 0; s < 2; ++s)
        #pragma unroll
        for (int r = 0; r < 4; ++r) {
            float v = lacc[s][r];
            v += __shfl_xor(v, 1);
            v += __shfl_xor(v, 2);
            v += __shfl_xor(v, 4);
            v += __shfl_xor(v, 8);
            invl[s][r] = 1.0f / v;
        }

    // =============== PASS 2: w[col] = sum_q attn[q,col] ===============
    for (int n0 = 0; n0 < SS; n0 += 32) {
        unsigned int mw[2][4];
        if constexpr (MBITS) {
            #pragma unroll
            for (int s = 0; s < 2; ++s)
                #pragma unroll
                for (int r = 0; r < 4; ++r)
                    mw[s][r] = mbits[mrowW[s][r] + (n0 >> 5)];
        }
        {
            f32x4 a0 = {0.f, 0.f, 0.f, 0.f}, a1 = {0.f, 0.f, 0.f, 0.f};
            qk_tile(n0, a0, a1);
            float wp = 0.0f;
            #pragma unroll
            for (int r = 0; r < 4; ++r) {
                wp += mtest(mw, 0, r, lr, n0) ? __expf(a0[r]) * invl[0][r] : 0.0f;
                wp += mtest(mw, 1, r, lr, n0) ? __expf(a1[r]) * invl[1][r] : 0.0f;
            }
            wp += __shfl_xor(wp, 16);
            wp += __shfl_xor(wp, 32);
            if (lane < 16) w_lds[wave][n0 + lr] = wp;
        }
        {
            f32x4 a0 = {0.f, 0.f, 0.f, 0.f}, a1 = {0.f, 0.f, 0.f, 0.f};
            qk_tile(n0 + 16, a0, a1);
            float wp = 0.0f;
            #pragma unroll
            for (int r = 0; r < 4; ++r) {
                wp += mtest(mw, 0, r, 16 + lr, n0 + 16) ? __expf(a0[r]) * invl[0][r] : 0.0f;
                wp += mtest(mw, 1, r, 16 + lr, n0 + 16) ? __expf(a1[r]) * invl[1][r] : 0.0f;
            }
            wp += __shfl_xor(wp, 16);
            wp += __shfl_xor(wp, 32);
            if (lane < 16) w_lds[wave][n0 + 16 + lr] = wp;
        }
    }
    __syncthreads();

    // combine 4 waves' w, then out[d] += sum_c w[c] * V[c][d]
    for (int c = tid; c < SS; c += 256)
        w_lds[0][c] = w_lds[0][c] + w_lds[1][c] + w_lds[2][c] + w_lds[3][c];
    __syncthreads();

    const int d  = tid & 63;
    const int kg = tid >> 6;
    float oacc = 0.0f;
    for (int c = kg; c < SS; c += 4)
        oacc = fmaf(w_lds[0][c], V[bhoff + (size_t)c * DD + d], oacc);
    red[kg][d] = oacc;
    __syncthreads();
    if (kg == 0)
        atomicAdd(&out[bh * DD + d], red[0][d] + red[1][d] + red[2][d] + red[3][d]);
}

extern "C" void kernel_launch(void* const* d_in, const int* in_sizes, int n_in,
                              void* d_out, int out_size, void* d_ws, size_t ws_size,
                              hipStream_t stream) {
    const float* Q    = (const float*)d_in[0];
    const float* K    = (const float*)d_in[1];
    const float* V    = (const float*)d_in[2];
    const int*   mask = (const int*)d_in[3];
    float* out = (float*)d_out;

    const size_t nelem    = (size_t)BB * HH * SS * DD;     // 4.19M
    const size_t mb_bytes = (size_t)BB * SS * SS / 8;      // 512 KB
    const size_t k_bytes  = 2 * nelem * sizeof(short);     // 16.8 MB

    hipMemsetAsync(out, 0, (size_t)BB * HH * DD * sizeof(float), stream);

    const dim3 grid(BB * HH * (SS / QT));                  // 512 blocks

    if (ws_size >= mb_bytes + k_bytes) {
        unsigned long long* mb = (unsigned long long*)d_ws;
        short* Kh = (short*)((char*)d_ws + mb_bytes);
        short* Kl = Kh + nelem;
        maskbits_kernel<<<(BB * SS * SS) / 256, 256, 0, stream>>>(mask, mb);
        split_kernel<<<1024, 256, 0, stream>>>(K, Kh, Kl, (int)(nelem / 4));
        attn_mfma<true, true><<<grid, 256, 0, stream>>>(
            Q, Kh, Kl, K, V, mask, (const unsigned int*)mb, out);
    } else if (ws_size >= mb_bytes) {
        unsigned long long* mb = (unsigned long long*)d_ws;
        maskbits_kernel<<<(BB * SS * SS) / 256, 256, 0, stream>>>(mask, mb);
        attn_mfma<false, true><<<grid, 256, 0, stream>>>(
            Q, nullptr, nullptr, K, V, mask, (const unsigned int*)mb, out);
    } else {
        attn_mfma<false, false><<<grid, 256, 0, stream>>>(
            Q, nullptr, nullptr, K, V, mask, nullptr, out);
    }
}

// Round 9
// 294.645 us; speedup vs baseline: 1.4284x; 1.0349x over previous
//
#include <hip/hip_runtime.h>
#include <hip/hip_bf16.h>
#include <math.h>

// B,H,S,D = 4,16,1024,64 ; out[b,h,d] = sum_q (softmax(QK^T/sqrt(D)) @ V)[q,d]
//                                     = sum_k w[k]*V[k,d],  w[k] = sum_q attn[q,k]
#define BB 4
#define HH 16
#define SS 1024
#define DD 64

typedef __attribute__((ext_vector_type(8))) short bf16x8;
typedef __attribute__((ext_vector_type(4))) float f32x4;

#define MFMA_BF16 __builtin_amdgcn_mfma_f32_16x16x32_bf16

__device__ __forceinline__ float4 ld4f(const float* p) {
    return *reinterpret_cast<const float4*>(p);
}

// split fp32 x into bf16 hi + bf16 lo (x ~= hi + lo, |lo| <= 2^-9 |x|)
__device__ __forceinline__ void bsplit(float x, short& h, short& l) {
    __hip_bfloat16 bh = __float2bfloat16(x);
    float rem = x - __bfloat162float(bh);
    __hip_bfloat16 bl = __float2bfloat16(rem);
    h = *reinterpret_cast<short*>(&bh);
    l = *reinterpret_cast<short*>(&bl);
}

// prep: K fp32 -> Kh, Kl bf16 arrays (workspace)
__global__ __launch_bounds__(256)
void split_kernel(const float* __restrict__ in, short* __restrict__ hi,
                  short* __restrict__ lo, int n4) {
    const float4* in4 = reinterpret_cast<const float4*>(in);
    for (int i = blockIdx.x * blockDim.x + threadIdx.x; i < n4;
         i += gridDim.x * blockDim.x) {
        float4 v = in4[i];
        short h0, h1, h2, h3, l0, l1, l2, l3;
        bsplit(v.x, h0, l0); bsplit(v.y, h1, l1);
        bsplit(v.z, h2, l2); bsplit(v.w, h3, l3);
        short4 hv = {h0, h1, h2, h3};
        short4 lv = {l0, l1, l2, l3};
        reinterpret_cast<short4*>(hi)[i] = hv;
        reinterpret_cast<short4*>(lo)[i] = lv;
    }
}

// prep: int32 mask -> bit mask (1 bit per element), wave-ballot packed.
__global__ __launch_bounds__(256)
void maskbits_kernel(const int* __restrict__ mask,
                     unsigned long long* __restrict__ bits) {
    const int tid = blockIdx.x * blockDim.x + threadIdx.x;
    const int widx = tid >> 6;
    const int lane = tid & 63;
    const unsigned long long bal = __ballot(mask[(size_t)widx * 64 + lane] != 0);
    if (lane == 0) bits[widx] = bal;
}

constexpr int QT = 128;      // q rows per block; 4 waves x 2 subtiles of 16
constexpr int MW = SS / 32;  // mask words per row (uint32 granularity)

// PRESPLIT: K fragments from pre-split bf16 hi/lo arrays, else in-register split.
// MBITS   : mask from packed bitmask, else raw int32 loads.
template <bool PRESPLIT, bool MBITS>
__global__ __launch_bounds__(256, 2)
void attn_mfma(const float* __restrict__ Q, const short* __restrict__ Kh,
               const short* __restrict__ Kl, const float* __restrict__ Kf,
               const float* __restrict__ V, const int* __restrict__ mask,
               const unsigned int* __restrict__ mbits, float* __restrict__ out) {
    __shared__ float w_lds[4][SS];   // per-wave column sums, 16 KB
    __shared__ float red[4][64];

    const int bid = blockIdx.x;
    // XCD-local mapping: bid%8 == bh%8, so all 8 q-tiles of one (b,h) land on
    // one XCD and its K-split slice (8 bh x 512 KB = 4 MB) fits that L2.
    // r6 (same mapping, QT=64): FETCH 34 MB. r7 (bh=bid/8): FETCH 205 MB.
    const int bh  = bid & 63;
    const int qt  = bid >> 6;             // 0..7
    const int b   = bh >> 4;
    const int tid  = threadIdx.x;
    const int wave = tid >> 6;
    const int lane = tid & 63;
    const int lg = lane >> 4;             // k-group / row-quarter
    const int lr = lane & 15;             // A row / B col within tile

    const size_t bhoff = (size_t)bh * SS * DD;
    const int q0 = qt * QT;
    const int m_base = q0 + wave * 32;    // this wave's 32 q rows

    // ---- preload Q fragments (scaled by 1/sqrt(D), split hi/lo) ----
    bf16x8 qh00, qh01, qh10, qh11, ql00, ql01, ql10, ql11;
    {
        auto loadq = [&](int s, int d, bf16x8& H, bf16x8& L) {
            const float* qp = Q + bhoff + (size_t)(m_base + s * 16 + lr) * DD
                              + d * 32 + lg * 8;
            float4 a = ld4f(qp), c = ld4f(qp + 4);
            float xs[8] = {a.x, a.y, a.z, a.w, c.x, c.y, c.z, c.w};
            #pragma unroll
            for (int j = 0; j < 8; ++j) {
                short hh, ll;
                bsplit(xs[j] * 0.125f, hh, ll);
                H[j] = hh; L[j] = ll;
            }
        };
        loadq(0, 0, qh00, ql00); loadq(0, 1, qh01, ql01);
        loadq(1, 0, qh10, ql10); loadq(1, 1, qh11, ql11);
    }

    // mask row bases: row = m_base + s*16 + lg*4 + r
    int mrowW[2][4];   // word-row base (MBITS)
    int mrowE[2][4];   // element-row base (raw)
    #pragma unroll
    for (int s = 0; s < 2; ++s)
        #pragma unroll
        for (int r = 0; r < 4; ++r) {
            const int row = b * SS + m_base + s * 16 + lg * 4 + r;
            mrowW[s][r] = row * MW;
            mrowE[s][r] = row * SS + lr;
        }

    const short* khp = Kh + bhoff + (size_t)lr * DD + lg * 8;
    const short* klp = Kl + bhoff + (size_t)lr * DD + lg * 8;
    const float* kfp = Kf + bhoff + (size_t)lr * DD + lg * 8;

    // 12 MFMAs: two independent acc chains (row subtiles s=0,1)
    auto qk_tile = [&](int n0, f32x4& acc0, f32x4& acc1) {
        bf16x8 kh0, kh1, kl0, kl1;
        if constexpr (PRESPLIT) {
            const short* kp = khp + (size_t)n0 * DD;
            kh0 = *(const bf16x8*)kp;
            kh1 = *(const bf16x8*)(kp + 32);
            const short* lp = klp + (size_t)n0 * DD;
            kl0 = *(const bf16x8*)lp;
            kl1 = *(const bf16x8*)(lp + 32);
        } else {
            const float* kp = kfp + (size_t)n0 * DD;
            float4 a = ld4f(kp), c = ld4f(kp + 4);
            float4 e = ld4f(kp + 32), g = ld4f(kp + 36);
            float x0[8] = {a.x, a.y, a.z, a.w, c.x, c.y, c.z, c.w};
            float x1[8] = {e.x, e.y, e.z, e.w, g.x, g.y, g.z, g.w};
            #pragma unroll
            for (int j = 0; j < 8; ++j) {
                short hh, ll;
                bsplit(x0[j], hh, ll);
                kh0[j] = hh; kl0[j] = ll;
                bsplit(x1[j], hh, ll);
                kh1[j] = hh; kl1[j] = ll;
            }
        }
        acc0 = MFMA_BF16(qh00, kh0, acc0, 0, 0, 0);
        acc1 = MFMA_BF16(qh10, kh0, acc1, 0, 0, 0);
        acc0 = MFMA_BF16(qh01, kh1, acc0, 0, 0, 0);
        acc1 = MFMA_BF16(qh11, kh1, acc1, 0, 0, 0);
        acc0 = MFMA_BF16(qh00, kl0, acc0, 0, 0, 0);
        acc1 = MFMA_BF16(qh10, kl0, acc1, 0, 0, 0);
        acc0 = MFMA_BF16(qh01, kl1, acc0, 0, 0, 0);
        acc1 = MFMA_BF16(qh11, kl1, acc1, 0, 0, 0);
        acc0 = MFMA_BF16(ql00, kh0, acc0, 0, 0, 0);
        acc1 = MFMA_BF16(ql10, kh0, acc1, 0, 0, 0);
        acc0 = MFMA_BF16(ql01, kh1, acc0, 0, 0, 0);
        acc1 = MFMA_BF16(ql11, kh1, acc1, 0, 0, 0);
    };

    // mask test for (subtile s, reg r), column bit = base bit within 32-word
    auto mtest = [&](const unsigned int mw[2][4], int s, int r, int bit,
                     int n0) -> bool {
        if constexpr (MBITS)
            return (mw[s][r] >> bit) & 1u;
        else
            return mask[mrowE[s][r] + n0] != 0;
    };

    // =============== PASS 1: row exp-sums l[q] ===============
    float lacc[2][4];
    #pragma unroll
    for (int s = 0; s < 2; ++s)
        #pragma unroll
        for (int r = 0; r < 4; ++r) lacc[s][r] = 0.0f;

    for (int n0 = 0; n0 < SS; n0 += 32) {
        unsigned int mw[2][4];
        if constexpr (MBITS) {
            #pragma unroll
            for (int s = 0; s < 2; ++s)
                #pragma unroll
                for (int r = 0; r < 4; ++r)
                    mw[s][r] = mbits[mrowW[s][r] + (n0 >> 5)];
        }
        {
            f32x4 a0 = {0.f, 0.f, 0.f, 0.f}, a1 = {0.f, 0.f, 0.f, 0.f};
            qk_tile(n0, a0, a1);
            #pragma unroll
            for (int r = 0; r < 4; ++r) {
                lacc[0][r] += mtest(mw, 0, r, lr, n0) ? __expf(a0[r]) : 0.0f;
                lacc[1][r] += mtest(mw, 1, r, lr, n0) ? __expf(a1[r]) : 0.0f;
            }
        }
        {
            f32x4 a0 = {0.f, 0.f, 0.f, 0.f}, a1 = {0.f, 0.f, 0.f, 0.f};
            qk_tile(n0 + 16, a0, a1);
            #pragma unroll
            for (int r = 0; r < 4; ++r) {
                lacc[0][r] += mtest(mw, 0, r, 16 + lr, n0 + 16) ? __expf(a0[r]) : 0.0f;
                lacc[1][r] += mtest(mw, 1, r, 16 + lr, n0 + 16) ? __expf(a1[r]) : 0.0f;
            }
        }
    }

    // reduce over the 16 col-lanes (same lg group) -> 1/l per row
    float invl[2][4];
    #pragma unroll
    for (int s = 0; s < 2; ++s)
        #pragma unroll
        for (int r = 0; r < 4; ++r) {
            float v = lacc[s][r];
            v += __shfl_xor(v, 1);
            v += __shfl_xor(v, 2);
            v += __shfl_xor(v, 4);
            v += __shfl_xor(v, 8);
            invl[s][r] = 1.0f / v;
        }

    // =============== PASS 2: w[col] = sum_q attn[q,col] ===============
    for (int n0 = 0; n0 < SS; n0 += 32) {
        unsigned int mw[2][4];
        if constexpr (MBITS) {
            #pragma unroll
            for (int s = 0; s < 2; ++s)
                #pragma unroll
                for (int r = 0; r < 4; ++r)
                    mw[s][r] = mbits[mrowW[s][r] + (n0 >> 5)];
        }
        {
            f32x4 a0 = {0.f, 0.f, 0.f, 0.f}, a1 = {0.f, 0.f, 0.f, 0.f};
            qk_tile(n0, a0, a1);
            float wp = 0.0f;
            #pragma unroll
            for (int r = 0; r < 4; ++r) {
                wp += mtest(mw, 0, r, lr, n0) ? __expf(a0[r]) * invl[0][r] : 0.0f;
                wp += mtest(mw, 1, r, lr, n0) ? __expf(a1[r]) * invl[1][r] : 0.0f;
            }
            wp += __shfl_xor(wp, 16);
            wp += __shfl_xor(wp, 32);
            if (lane < 16) w_lds[wave][n0 + lr] = wp;
        }
        {
            f32x4 a0 = {0.f, 0.f, 0.f, 0.f}, a1 = {0.f, 0.f, 0.f, 0.f};
            qk_tile(n0 + 16, a0, a1);
            float wp = 0.0f;
            #pragma unroll
            for (int r = 0; r < 4; ++r) {
                wp += mtest(mw, 0, r, 16 + lr, n0 + 16) ? __expf(a0[r]) * invl[0][r] : 0.0f;
                wp += mtest(mw, 1, r, 16 + lr, n0 + 16) ? __expf(a1[r]) * invl[1][r] : 0.0f;
            }
            wp += __shfl_xor(wp, 16);
            wp += __shfl_xor(wp, 32);
            if (lane < 16) w_lds[wave][n0 + 16 + lr] = wp;
        }
    }
    __syncthreads();

    // combine 4 waves' w, then out[d] += sum_c w[c] * V[c][d]
    for (int c = tid; c < SS; c += 256)
        w_lds[0][c] = w_lds[0][c] + w_lds[1][c] + w_lds[2][c] + w_lds[3][c];
    __syncthreads();

    const int d  = tid & 63;
    const int kg = tid >> 6;
    float oacc = 0.0f;
    for (int c = kg; c < SS; c += 4)
        oacc = fmaf(w_lds[0][c], V[bhoff + (size_t)c * DD + d], oacc);
    red[kg][d] = oacc;
    __syncthreads();
    if (kg == 0)
        atomicAdd(&out[bh * DD + d], red[0][d] + red[1][d] + red[2][d] + red[3][d]);
}

extern "C" void kernel_launch(void* const* d_in, const int* in_sizes, int n_in,
                              void* d_out, int out_size, void* d_ws, size_t ws_size,
                              hipStream_t stream) {
    const float* Q    = (const float*)d_in[0];
    const float* K    = (const float*)d_in[1];
    const float* V    = (const float*)d_in[2];
    const int*   mask = (const int*)d_in[3];
    float* out = (float*)d_out;

    const size_t nelem    = (size_t)BB * HH * SS * DD;     // 4.19M
    const size_t mb_bytes = (size_t)BB * SS * SS / 8;      // 512 KB
    const size_t k_bytes  = 2 * nelem * sizeof(short);     // 16.8 MB

    hipMemsetAsync(out, 0, (size_t)BB * HH * DD * sizeof(float), stream);

    const dim3 grid(BB * HH * (SS / QT));                  // 512 blocks

    if (ws_size >= mb_bytes + k_bytes) {
        unsigned long long* mb = (unsigned long long*)d_ws;
        short* Kh = (short*)((char*)d_ws + mb_bytes);
        short* Kl = Kh + nelem;
        maskbits_kernel<<<(BB * SS * SS) / 256, 256, 0, stream>>>(mask, mb);
        split_kernel<<<1024, 256, 0, stream>>>(K, Kh, Kl, (int)(nelem / 4));
        attn_mfma<true, true><<<grid, 256, 0, stream>>>(
            Q, Kh, Kl, K, V, mask, (const unsigned int*)mb, out);
    } else if (ws_size >= mb_bytes) {
        unsigned long long* mb = (unsigned long long*)d_ws;
        maskbits_kernel<<<(BB * SS * SS) / 256, 256, 0, stream>>>(mask, mb);
        attn_mfma<false, true><<<grid, 256, 0, stream>>>(
            Q, nullptr, nullptr, K, V, mask, (const unsigned int*)mb, out);
    } else {
        attn_mfma<false, false><<<grid, 256, 0, stream>>>(
            Q, nullptr, nullptr, K, V, mask, nullptr, out);
    }
}

// Round 11
// 282.958 us; speedup vs baseline: 1.4874x; 1.0413x over previous
//
#include <hip/hip_runtime.h>
#include <hip/hip_bf16.h>
#include <math.h>

// B,H,S,D = 4,16,1024,64 ; out[b,h,d] = sum_q (softmax(QK^T/sqrt(D)) @ V)[q,d]
//                                     = sum_k w[k]*V[k,d],  w[k] = sum_q attn[q,k]
#define BB 4
#define HH 16
#define SS 1024
#define DD 64

typedef __attribute__((ext_vector_type(8))) short bf16x8;
typedef __attribute__((ext_vector_type(4))) float f32x4;

#define MFMA_BF16 __builtin_amdgcn_mfma_f32_16x16x32_bf16

__device__ __forceinline__ float4 ld4f(const float* p) {
    return *reinterpret_cast<const float4*>(p);
}

// split fp32 x into bf16 hi + bf16 lo (x ~= hi + lo, |lo| <= 2^-9 |x|)
__device__ __forceinline__ void bsplit(float x, short& h, short& l) {
    __hip_bfloat16 bh = __float2bfloat16(x);
    float rem = x - __bfloat162float(bh);
    __hip_bfloat16 bl = __float2bfloat16(rem);
    h = *reinterpret_cast<short*>(&bh);
    l = *reinterpret_cast<short*>(&bl);
}

// prep: K fp32 -> Kh, Kl bf16 arrays (workspace)
__global__ __launch_bounds__(256)
void split_kernel(const float* __restrict__ in, short* __restrict__ hi,
                  short* __restrict__ lo, int n4) {
    const float4* in4 = reinterpret_cast<const float4*>(in);
    for (int i = blockIdx.x * blockDim.x + threadIdx.x; i < n4;
         i += gridDim.x * blockDim.x) {
        float4 v = in4[i];
        short h0, h1, h2, h3, l0, l1, l2, l3;
        bsplit(v.x, h0, l0); bsplit(v.y, h1, l1);
        bsplit(v.z, h2, l2); bsplit(v.w, h3, l3);
        short4 hv = {h0, h1, h2, h3};
        short4 lv = {l0, l1, l2, l3};
        reinterpret_cast<short4*>(hi)[i] = hv;
        reinterpret_cast<short4*>(lo)[i] = lv;
    }
}

// prep: int32 mask -> bit mask (1 bit per element), wave-ballot packed.
__global__ __launch_bounds__(256)
void maskbits_kernel(const int* __restrict__ mask,
                     unsigned long long* __restrict__ bits) {
    const int tid = blockIdx.x * blockDim.x + threadIdx.x;
    const int widx = tid >> 6;
    const int lane = tid & 63;
    const unsigned long long bal = __ballot(mask[(size_t)widx * 64 + lane] != 0);
    if (lane == 0) bits[widx] = bal;
}

constexpr int QT = 128;      // q rows per block; 4 waves x 2 subtiles of 16
constexpr int MW = SS / 32;  // mask words per row (uint32 granularity)

struct KFrag { bf16x8 kh0, kh1, kl0, kl1; };   // one 16-col tile, hi+lo, K=64

// PRESPLIT: K fragments from pre-split bf16 hi/lo arrays, else in-register split.
// MBITS   : mask from packed bitmask, else raw int32 loads.
template <bool PRESPLIT, bool MBITS>
__global__ __launch_bounds__(256, 2)
void attn_mfma(const float* __restrict__ Q, const short* __restrict__ Kh,
               const short* __restrict__ Kl, const float* __restrict__ Kf,
               const float* __restrict__ V, const int* __restrict__ mask,
               const unsigned int* __restrict__ mbits, float* __restrict__ out) {
    __shared__ float w_lds[4][SS];   // per-wave column sums, 16 KB
    __shared__ float red[4][64];

    const int bid = blockIdx.x;
    // XCD-local mapping: bid%8 == bh%8 -> one (b,h)'s K slice stays in one L2.
    // (r7 vs r9: FETCH 205 MB -> 34 MB; dur unchanged -> not memory-bound.)
    const int bh  = bid & 63;
    const int qt  = bid >> 6;             // 0..7
    const int b   = bh >> 4;
    const int tid  = threadIdx.x;
    const int wave = tid >> 6;
    const int lane = tid & 63;
    const int lg = lane >> 4;             // k-group / row-quarter
    const int lr = lane & 15;             // A row / B col within tile

    const size_t bhoff = (size_t)bh * SS * DD;
    const int q0 = qt * QT;
    const int m_base = q0 + wave * 32;    // this wave's 32 q rows

    // ---- preload Q fragments (scaled by 1/sqrt(D), split hi/lo) ----
    bf16x8 qh00, qh01, qh10, qh11, ql00, ql01, ql10, ql11;
    {
        auto loadq = [&](int s, int d, bf16x8& H, bf16x8& L) {
            const float* qp = Q + bhoff + (size_t)(m_base + s * 16 + lr) * DD
                              + d * 32 + lg * 8;
            float4 a = ld4f(qp), c = ld4f(qp + 4);
            float xs[8] = {a.x, a.y, a.z, a.w, c.x, c.y, c.z, c.w};
            #pragma unroll
            for (int j = 0; j < 8; ++j) {
                short hh, ll;
                bsplit(xs[j] * 0.125f, hh, ll);
                H[j] = hh; L[j] = ll;
            }
        };
        loadq(0, 0, qh00, ql00); loadq(0, 1, qh01, ql01);
        loadq(1, 0, qh10, ql10); loadq(1, 1, qh11, ql11);
    }

    // mask row bases: row = m_base + s*16 + lg*4 + r
    int mrowW[2][4];   // word-row base (MBITS)
    int mrowE[2][4];   // element-row base (raw)
    #pragma unroll
    for (int s = 0; s < 2; ++s)
        #pragma unroll
        for (int r = 0; r < 4; ++r) {
            const int row = b * SS + m_base + s * 16 + lg * 4 + r;
            mrowW[s][r] = row * MW;
            mrowE[s][r] = row * SS + lr;
        }

    const short* khp = Kh + bhoff + (size_t)lr * DD + lg * 8;
    const short* klp = Kl + bhoff + (size_t)lr * DD + lg * 8;
    const float* kfp = Kf + bhoff + (size_t)lr * DD + lg * 8;

    // issue the 4 vector loads for one 16-col tile
    auto load_frag = [&](int n0) -> KFrag {
        KFrag f;
        if constexpr (PRESPLIT) {
            const short* kp = khp + (size_t)n0 * DD;
            f.kh0 = *(const bf16x8*)kp;
            f.kh1 = *(const bf16x8*)(kp + 32);
            const short* lp = klp + (size_t)n0 * DD;
            f.kl0 = *(const bf16x8*)lp;
            f.kl1 = *(const bf16x8*)(lp + 32);
        } else {
            const float* kp = kfp + (size_t)n0 * DD;
            float4 a = ld4f(kp), c = ld4f(kp + 4);
            float4 e = ld4f(kp + 32), g = ld4f(kp + 36);
            float x0[8] = {a.x, a.y, a.z, a.w, c.x, c.y, c.z, c.w};
            float x1[8] = {e.x, e.y, e.z, e.w, g.x, g.y, g.z, g.w};
            #pragma unroll
            for (int j = 0; j < 8; ++j) {
                short hh, ll;
                bsplit(x0[j], hh, ll);
                f.kh0[j] = hh; f.kl0[j] = ll;
                bsplit(x1[j], hh, ll);
                f.kh1[j] = hh; f.kl1[j] = ll;
            }
        }
        return f;
    };

    auto load_mw = [&](int n0, unsigned int mw[2][4]) {
        if constexpr (MBITS) {
            #pragma unroll
            for (int s = 0; s < 2; ++s)
                #pragma unroll
                for (int r = 0; r < 4; ++r)
                    mw[s][r] = mbits[mrowW[s][r] + (n0 >> 5)];
        }
    };

    // 12 MFMAs on the current fragment: two independent acc chains
    auto qk_compute = [&](const KFrag& f, f32x4& acc0, f32x4& acc1) {
        acc0 = MFMA_BF16(qh00, f.kh0, acc0, 0, 0, 0);
        acc1 = MFMA_BF16(qh10, f.kh0, acc1, 0, 0, 0);
        acc0 = MFMA_BF16(qh01, f.kh1, acc0, 0, 0, 0);
        acc1 = MFMA_BF16(qh11, f.kh1, acc1, 0, 0, 0);
        acc0 = MFMA_BF16(qh00, f.kl0, acc0, 0, 0, 0);
        acc1 = MFMA_BF16(qh10, f.kl0, acc1, 0, 0, 0);
        acc0 = MFMA_BF16(qh01, f.kl1, acc0, 0, 0, 0);
        acc1 = MFMA_BF16(qh11, f.kl1, acc1, 0, 0, 0);
        acc0 = MFMA_BF16(ql00, f.kh0, acc0, 0, 0, 0);
        acc1 = MFMA_BF16(ql10, f.kh0, acc1, 0, 0, 0);
        acc0 = MFMA_BF16(ql01, f.kh1, acc0, 0, 0, 0);
        acc1 = MFMA_BF16(ql11, f.kh1, acc1, 0, 0, 0);
    };

    // mask test for (subtile s, reg r); bit = column bit within the 32-word
    auto mtest = [&](const unsigned int mw[2][4], int s, int r, int bit,
                     int n0) -> bool {
        if constexpr (MBITS)
            return (mw[s][r] >> bit) & 1u;
        else
            return mask[mrowE[s][r] + n0] != 0;
    };

    // =============== PASS 1: row exp-sums l[q] (prefetch-pipelined) =========
    float lacc[2][4];
    #pragma unroll
    for (int s = 0; s < 2; ++s)
        #pragma unroll
        for (int r = 0; r < 4; ++r) lacc[s][r] = 0.0f;

    {
        KFrag fA = load_frag(0), fB = load_frag(16);
        unsigned int mw[2][4];
        load_mw(0, mw);
        for (int n0 = 0; n0 < SS; n0 += 32) {
            const int nn = (n0 + 32) & (SS - 1);   // wrap: last prefetch benign
            KFrag nA = load_frag(nn), nB = load_frag(nn + 16);
            unsigned int nmw[2][4];
            load_mw(nn, nmw);

            f32x4 a0 = {0.f, 0.f, 0.f, 0.f}, a1 = {0.f, 0.f, 0.f, 0.f};
            qk_compute(fA, a0, a1);
            #pragma unroll
            for (int r = 0; r < 4; ++r) {
                lacc[0][r] += mtest(mw, 0, r, lr, n0) ? __expf(a0[r]) : 0.0f;
                lacc[1][r] += mtest(mw, 1, r, lr, n0) ? __expf(a1[r]) : 0.0f;
            }
            f32x4 b0 = {0.f, 0.f, 0.f, 0.f}, b1 = {0.f, 0.f, 0.f, 0.f};
            qk_compute(fB, b0, b1);
            #pragma unroll
            for (int r = 0; r < 4; ++r) {
                lacc[0][r] += mtest(mw, 0, r, 16 + lr, n0 + 16) ? __expf(b0[r]) : 0.0f;
                lacc[1][r] += mtest(mw, 1, r, 16 + lr, n0 + 16) ? __expf(b1[r]) : 0.0f;
            }

            fA = nA; fB = nB;
            #pragma unroll
            for (int s = 0; s < 2; ++s)
                #pragma unroll
                for (int r = 0; r < 4; ++r) mw[s][r] = nmw[s][r];
        }
    }

    // reduce over the 16 col-lanes (same lg group) -> 1/l per row
    float invl[2][4];
    #pragma unroll
    for (int s = 0; s < 2; ++s)
        #pragma unroll
        for (int r = 0; r < 4; ++r) {
            float v = lacc[s][r];
            v += __shfl_xor(v, 1);
            v += __shfl_xor(v, 2);
            v += __shfl_xor(v, 4);
            v += __shfl_xor(v, 8);
            invl[s][r] = 1.0f / v;
        }

    // =============== PASS 2: w[col] = sum_q attn[q,col] (pipelined) =========
    {
        KFrag fA = load_frag(0), fB = load_frag(16);
        unsigned int mw[2][4];
        load_mw(0, mw);
        for (int n0 = 0; n0 < SS; n0 += 32) {
            const int nn = (n0 + 32) & (SS - 1);
            KFrag nA = load_frag(nn), nB = load_frag(nn + 16);
            unsigned int nmw[2][4];
            load_mw(nn, nmw);

            f32x4 a0 = {0.f, 0.f, 0.f, 0.f}, a1 = {0.f, 0.f, 0.f, 0.f};
            qk_compute(fA, a0, a1);
            float wp0 = 0.0f;
            #pragma unroll
            for (int r = 0; r < 4; ++r) {
                wp0 += mtest(mw, 0, r, lr, n0) ? __expf(a0[r]) * invl[0][r] : 0.0f;
                wp0 += mtest(mw, 1, r, lr, n0) ? __expf(a1[r]) * invl[1][r] : 0.0f;
            }
            wp0 += __shfl_xor(wp0, 16);
            wp0 += __shfl_xor(wp0, 32);
            if (lane < 16) w_lds[wave][n0 + lr] = wp0;

            f32x4 b0 = {0.f, 0.f, 0.f, 0.f}, b1 = {0.f, 0.f, 0.f, 0.f};
            qk_compute(fB, b0, b1);
            float wp1 = 0.0f;
            #pragma unroll
            for (int r = 0; r < 4; ++r) {
                wp1 += mtest(mw, 0, r, 16 + lr, n0 + 16) ? __expf(b0[r]) * invl[0][r] : 0.0f;
                wp1 += mtest(mw, 1, r, 16 + lr, n0 + 16) ? __expf(b1[r]) * invl[1][r] : 0.0f;
            }
            wp1 += __shfl_xor(wp1, 16);
            wp1 += __shfl_xor(wp1, 32);
            if (lane < 16) w_lds[wave][n0 + 16 + lr] = wp1;

            fA = nA; fB = nB;
            #pragma unroll
            for (int s = 0; s < 2; ++s)
                #pragma unroll
                for (int r = 0; r < 4; ++r) mw[s][r] = nmw[s][r];
        }
    }
    __syncthreads();

    // combine 4 waves' w, then out[d] += sum_c w[c] * V[c][d]
    for (int c = tid; c < SS; c += 256)
        w_lds[0][c] = w_lds[0][c] + w_lds[1][c] + w_lds[2][c] + w_lds[3][c];
    __syncthreads();

    const int d  = tid & 63;
    const int kg = tid >> 6;
    float oacc = 0.0f;
    for (int c = kg; c < SS; c += 4)
        oacc = fmaf(w_lds[0][c], V[bhoff + (size_t)c * DD + d], oacc);
    red[kg][d] = oacc;
    __syncthreads();
    if (kg == 0)
        atomicAdd(&out[bh * DD + d], red[0][d] + red[1][d] + red[2][d] + red[3][d]);
}

extern "C" void kernel_launch(void* const* d_in, const int* in_sizes, int n_in,
                              void* d_out, int out_size, void* d_ws, size_t ws_size,
                              hipStream_t stream) {
    const float* Q    = (const float*)d_in[0];
    const float* K    = (const float*)d_in[1];
    const float* V    = (const float*)d_in[2];
    const int*   mask = (const int*)d_in[3];
    float* out = (float*)d_out;

    const size_t nelem    = (size_t)BB * HH * SS * DD;     // 4.19M
    const size_t mb_bytes = (size_t)BB * SS * SS / 8;      // 512 KB
    const size_t k_bytes  = 2 * nelem * sizeof(short);     // 16.8 MB

    hipMemsetAsync(out, 0, (size_t)BB * HH * DD * sizeof(float), stream);

    const dim3 grid(BB * HH * (SS / QT));                  // 512 blocks

    if (ws_size >= mb_bytes + k_bytes) {
        unsigned long long* mb = (unsigned long long*)d_ws;
        short* Kh = (short*)((char*)d_ws + mb_bytes);
        short* Kl = Kh + nelem;
        maskbits_kernel<<<(BB * SS * SS) / 256, 256, 0, stream>>>(mask, mb);
        split_kernel<<<1024, 256, 0, stream>>>(K, Kh, Kl, (int)(nelem / 4));
        attn_mfma<true, true><<<grid, 256, 0, stream>>>(
            Q, Kh, Kl, K, V, mask, (const unsigned int*)mb, out);
    } else if (ws_size >= mb_bytes) {
        unsigned long long* mb = (unsigned long long*)d_ws;
        maskbits_kernel<<<(BB * SS * SS) / 256, 256, 0, stream>>>(mask, mb);
        attn_mfma<false, true><<<grid, 256, 0, stream>>>(
            Q, nullptr, nullptr, K, V, mask, (const unsigned int*)mb, out);
    } else {
        attn_mfma<false, false><<<grid, 256, 0, stream>>>(
            Q, nullptr, nullptr, K, V, mask, nullptr, out);
    }
}

// Round 12
// 239.954 us; speedup vs baseline: 1.7540x; 1.1792x over previous
//
#include <hip/hip_runtime.h>
#include <hip/hip_bf16.h>
#include <math.h>

// B,H,S,D = 4,16,1024,64
// out[b,h,d] = sum_q softmax(QK^T/8)[q,:] @ V  summed over q
// ONE-PASS form: y[q,d] = sum_k e[q,k] V[k,d], l[q] = sum_k e[q,k],
//                out[d] = sum_q y[q,d]/l[q]           (no max-subtract; s<~6)
#define BB 4
#define HH 16
#define SS 1024
#define DD 64

typedef __attribute__((ext_vector_type(8))) short bf16x8;
typedef __attribute__((ext_vector_type(4))) short bf16x4;
typedef __attribute__((ext_vector_type(4))) float f32x4;

#define MFMA32 __builtin_amdgcn_mfma_f32_16x16x32_bf16
#define MFMA16 __builtin_amdgcn_mfma_f32_16x16x16bf16_1k

__device__ __forceinline__ float4 ld4f(const float* p) {
    return *reinterpret_cast<const float4*>(p);
}

// split fp32 x into bf16 hi + bf16 lo (x ~= hi + lo)
__device__ __forceinline__ void bsplit(float x, short& h, short& l) {
    __hip_bfloat16 bh = __float2bfloat16(x);
    float rem = x - __bfloat162float(bh);
    __hip_bfloat16 bl = __float2bfloat16(rem);
    h = *reinterpret_cast<short*>(&bh);
    l = *reinterpret_cast<short*>(&bl);
}

// prep: K fp32 -> Kh, Kl bf16 arrays
__global__ __launch_bounds__(256)
void split_kernel(const float* __restrict__ in, short* __restrict__ hi,
                  short* __restrict__ lo, int n4) {
    const float4* in4 = reinterpret_cast<const float4*>(in);
    for (int i = blockIdx.x * blockDim.x + threadIdx.x; i < n4;
         i += gridDim.x * blockDim.x) {
        float4 v = in4[i];
        short h0, h1, h2, h3, l0, l1, l2, l3;
        bsplit(v.x, h0, l0); bsplit(v.y, h1, l1);
        bsplit(v.z, h2, l2); bsplit(v.w, h3, l3);
        bf16x4 hv = {h0, h1, h2, h3};
        bf16x4 lv = {l0, l1, l2, l3};
        *reinterpret_cast<bf16x4*>(hi + (size_t)i * 4) = hv;
        *reinterpret_cast<bf16x4*>(lo + (size_t)i * 4) = lv;
    }
}

// prep: int32 mask -> packed bits (bit i of word w = mask[64w+i] != 0)
__global__ __launch_bounds__(256)
void maskbits_kernel(const int* __restrict__ mask,
                     unsigned long long* __restrict__ bits) {
    const int tid = blockIdx.x * blockDim.x + threadIdx.x;
    const int widx = tid >> 6;
    const int lane = tid & 63;
    const unsigned long long bal = __ballot(mask[(size_t)widx * 64 + lane] != 0);
    if (lane == 0) bits[widx] = bal;
}

// prep: pack V into PV-B-fragment-linear bf16 hi/lo blocks.
// Block (bh, kt, dt, p): 256 bf16; lane ln holds j=0..3 -> V[kt*16+(ln>>4)*4+j][dt*16+(ln&15)]
__global__ __launch_bounds__(256)
void vpack_kernel(const float* __restrict__ V, short* __restrict__ Vp) {
    const int blk = blockIdx.x;              // bh*64 + kt
    const int bh = blk >> 6, kt = blk & 63;
    const int dt = threadIdx.x >> 6, ln = threadIdx.x & 63;
    bf16x4 hv, lv;
    #pragma unroll
    for (int j = 0; j < 4; ++j) {
        float v = V[(size_t)bh * SS * DD + (size_t)(kt * 16 + (ln >> 4) * 4 + j) * DD
                    + dt * 16 + (ln & 15)];
        short h, l;
        bsplit(v, h, l);
        hv[j] = h; lv[j] = l;
    }
    size_t base = ((size_t)(bh * 64 + kt) * 4 + dt) * 2 * 256;
    *reinterpret_cast<bf16x4*>(Vp + base + ln * 4) = hv;
    *reinterpret_cast<bf16x4*>(Vp + base + 256 + ln * 4) = lv;
}

constexpr int QT = 128;      // q rows per block; 4 waves x 2 subtiles of 16
constexpr int MW = SS / 32;  // mask uint32 words per row

// VPACK: V fragments from packed workspace, else fp32 V + in-register split.
template <bool VPACK>
__global__ __launch_bounds__(256, 2)
void attn_onepass(const float* __restrict__ Q, const short* __restrict__ Kh,
                  const short* __restrict__ Kl, const float* __restrict__ V,
                  const short* __restrict__ Vp,
                  const unsigned int* __restrict__ mbits,
                  float* __restrict__ out) {
    const int bid = blockIdx.x;
    // XCD-local mapping: bid%8 == bh%8 (one bh's K/V slice stays in one L2)
    const int bh = bid & 63;
    const int qt = bid >> 6;             // 0..7
    const int b  = bh >> 4;
    const int tid = threadIdx.x, wave = tid >> 6, lane = tid & 63;
    const int lg = lane >> 4, lr = lane & 15;

    const size_t bhoff = (size_t)bh * SS * DD;
    const int qsub0 = qt * QT + wave * 32;   // subtile s covers rows qsub0+s*16 ..+15

    // ---- Q fragments (B operand of swapped QK): col=lr -> q, k-dim over d ----
    bf16x8 qh[2][2], ql[2][2];
    #pragma unroll
    for (int s = 0; s < 2; ++s)
        #pragma unroll
        for (int ds = 0; ds < 2; ++ds) {
            const float* qp = Q + bhoff + (size_t)(qsub0 + s * 16 + lr) * DD
                              + ds * 32 + lg * 8;
            float4 a = ld4f(qp), c = ld4f(qp + 4);
            float xs[8] = {a.x, a.y, a.z, a.w, c.x, c.y, c.z, c.w};
            #pragma unroll
            for (int j = 0; j < 8; ++j) {
                short h, l;
                bsplit(xs[j] * 0.125f, h, l);
                qh[s][ds][j] = h; ql[s][ds][j] = l;
            }
        }

    // mask word base per subtile (q-row = qsub0+s*16+lr is lane-local in S^T)
    int mrowW[2];
    #pragma unroll
    for (int s = 0; s < 2; ++s)
        mrowW[s] = (b * SS + qsub0 + s * 16 + lr) * MW;

    const short* khp = Kh + bhoff + (size_t)lr * DD + lg * 8;
    const short* klp = Kl + bhoff + (size_t)lr * DD + lg * 8;
    const short* vpb = Vp + (size_t)bh * 512 * 256 + lane * 4;

    f32x4 y[2][4];
    #pragma unroll
    for (int s = 0; s < 2; ++s)
        #pragma unroll
        for (int dt = 0; dt < 4; ++dt) y[s][dt] = {0.f, 0.f, 0.f, 0.f};
    float lsum[2] = {0.f, 0.f};

    for (int n0 = 0; n0 < SS; n0 += 32) {
        const unsigned int mwA = mbits[mrowW[0] + (n0 >> 5)];
        const unsigned int mwB = mbits[mrowW[1] + (n0 >> 5)];
        #pragma unroll
        for (int t = 0; t < 2; ++t) {
            const int kt = (n0 >> 4) + t;
            // K fragments (A operand): row=lr -> k = kt*16+lr
            const short* kp = khp + (size_t)kt * 16 * DD;
            bf16x8 kh0 = *(const bf16x8*)kp;
            bf16x8 kh1 = *(const bf16x8*)(kp + 32);
            const short* lp = klp + (size_t)kt * 16 * DD;
            bf16x8 kl0 = *(const bf16x8*)lp;
            bf16x8 kl1 = *(const bf16x8*)(lp + 32);
            // V fragments for this k-tile
            bf16x4 vhi[4], vlo[4];
            if constexpr (VPACK) {
                #pragma unroll
                for (int dt = 0; dt < 4; ++dt) {
                    vhi[dt] = *(const bf16x4*)(vpb + ((size_t)(kt * 4 + dt) * 2) * 256);
                    vlo[dt] = *(const bf16x4*)(vpb + ((size_t)(kt * 4 + dt) * 2 + 1) * 256);
                }
            } else {
                #pragma unroll
                for (int dt = 0; dt < 4; ++dt)
                    #pragma unroll
                    for (int j = 0; j < 4; ++j) {
                        float vv = V[bhoff + (size_t)(kt * 16 + lg * 4 + j) * DD
                                     + dt * 16 + lr];
                        short h, l;
                        bsplit(vv, h, l);
                        vhi[dt][j] = h; vlo[dt][j] = l;
                    }
            }
            #pragma unroll
            for (int s = 0; s < 2; ++s) {
                // swapped QK^T: S^T tile, lane holds col q=lr, rows k=lg*4+r
                f32x4 acc = {0.f, 0.f, 0.f, 0.f};
                acc = MFMA32(kh0, qh[s][0], acc, 0, 0, 0);
                acc = MFMA32(kh1, qh[s][1], acc, 0, 0, 0);
                acc = MFMA32(kl0, qh[s][0], acc, 0, 0, 0);
                acc = MFMA32(kl1, qh[s][1], acc, 0, 0, 0);
                acc = MFMA32(kh0, ql[s][0], acc, 0, 0, 0);
                acc = MFMA32(kh1, ql[s][1], acc, 0, 0, 0);
                const unsigned int mw = s ? mwB : mwA;
                bf16x4 ehi, elo;
                float es = 0.f;
                #pragma unroll
                for (int r = 0; r < 4; ++r) {
                    const int bit = t * 16 + lg * 4 + r;
                    const float e = ((mw >> bit) & 1u) ? __expf(acc[r]) : 0.0f;
                    es += e;
                    short h, l;
                    bsplit(e, h, l);
                    ehi[r] = h; elo[r] = l;
                }
                lsum[s] += es;
                // PV: e sits exactly in 16x16x16 A-layout (row=q=lr, k=lg*4+r)
                #pragma unroll
                for (int dt = 0; dt < 4; ++dt) {
                    y[s][dt] = MFMA16(ehi, vhi[dt], y[s][dt], 0, 0, 0);
                    y[s][dt] = MFMA16(elo, vhi[dt], y[s][dt], 0, 0, 0);
                    y[s][dt] = MFMA16(ehi, vlo[dt], y[s][dt], 0, 0, 0);
                }
            }
        }
    }

    // ---- epilogue: l-reduce, divide, q-reduce, atomic out ----
    float linv[2][4];
    #pragma unroll
    for (int s = 0; s < 2; ++s) {
        float lt = lsum[s];
        lt += __shfl_xor(lt, 16);
        lt += __shfl_xor(lt, 32);        // lt = l[q=lane&15], all lanes
        #pragma unroll
        for (int r = 0; r < 4; ++r)
            linv[s][r] = 1.0f / __shfl(lt, lg * 4 + r);   // l at q=lg*4+r
    }
    #pragma unroll
    for (int dt = 0; dt < 4; ++dt) {
        float p = 0.f;
        #pragma unroll
        for (int s = 0; s < 2; ++s)
            #pragma unroll
            for (int r = 0; r < 4; ++r)
                p += y[s][dt][r] * linv[s][r];
        p += __shfl_xor(p, 16);
        p += __shfl_xor(p, 32);          // sum over the 4 lane-groups (q chunks)
        if (lane < 16) atomicAdd(&out[bh * DD + dt * 16 + lane], p);
    }
}

extern "C" void kernel_launch(void* const* d_in, const int* in_sizes, int n_in,
                              void* d_out, int out_size, void* d_ws, size_t ws_size,
                              hipStream_t stream) {
    const float* Q    = (const float*)d_in[0];
    const float* K    = (const float*)d_in[1];
    const float* V    = (const float*)d_in[2];
    const int*   mask = (const int*)d_in[3];
    float* out = (float*)d_out;

    const size_t nelem    = (size_t)BB * HH * SS * DD;     // 4.19M
    const size_t mb_bytes = (size_t)BB * SS * SS / 8;      // 512 KB
    const size_t k_bytes  = 2 * nelem * sizeof(short);     // 16.8 MB
    const size_t v_bytes  = 2 * nelem * sizeof(short);     // 16.8 MB (packed V hi+lo)

    unsigned long long* mb = (unsigned long long*)d_ws;
    short* Kh = (short*)((char*)d_ws + mb_bytes);
    short* Kl = Kh + nelem;

    hipMemsetAsync(out, 0, (size_t)BB * HH * DD * sizeof(float), stream);
    maskbits_kernel<<<(BB * SS * SS) / 256, 256, 0, stream>>>(mask, mb);
    split_kernel<<<1024, 256, 0, stream>>>(K, Kh, Kl, (int)(nelem / 4));

    const dim3 grid(BB * HH * (SS / QT));                  // 512 blocks

    if (ws_size >= mb_bytes + k_bytes + v_bytes) {
        short* Vp = Kl + nelem;
        vpack_kernel<<<BB * HH * (SS / 16), 256, 0, stream>>>(V, Vp);
        attn_onepass<true><<<grid, 256, 0, stream>>>(
            Q, Kh, Kl, V, Vp, (const unsigned int*)mb, out);
    } else {
        attn_onepass<false><<<grid, 256, 0, stream>>>(
            Q, Kh, Kl, V, nullptr, (const unsigned int*)mb, out);
    }
}